// Round 11
// baseline (565.746 us; speedup 1.0000x reference)
//
#include <hip/hip_runtime.h>

typedef unsigned long long u64;
typedef unsigned int u32;

// ---------------- problem constants ----------------
constexpr int B_ = 2;
constexpr int C_ = 7;
constexpr int V_ = 32 * 256 * 256;        // 2097152
constexpr int NS_ = 17;                   // segments incl background
constexpr int NI_ = 16;                   // instances

// lovasz histogram: 16 bins over err in [0,2]
constexpr int NB = 16;
constexpr float BSCALE = 8.0f;            // err*8 -> bin
constexpr float BINW = 0.125f;

// k_stats per-lane LDS: 17 segs x 7 packed u32 fields, stride 121 (odd -> 2-way banks)
constexpr int SFLD = 7;
constexpr int SSTR = NS_ * SFLD + 2;      // 121 words
constexpr float QS = 4096.0f;             // (sig+8) scale ; per-lane <=32 voxels
constexpr float RS = 2048.0f;             // sig^2 scale
constexpr double SEED_SCALE = 16777216.0; // 2^24

// k_hist per-lane LDS: [16][2][16] u8 = 512 B + 4 pad = 516 B (129 words, odd)
constexpr int HSTR_B = 516;
constexpr int HSTR_W = 129;

// ---------------- kernel 1: segmented stats (per-lane LDS, plain RMW) ----------------
// statsI per (b,s): 0 cnt | 1 Sx | 2 Sy | 3 Sz | 4 Sq0 | 5 Sq1 | 6 Sq2 | 7 Sr0 | 8 Sr1 | 9 Sr2
__global__ __launch_bounds__(64) void k_stats(const float* __restrict__ pred,
                                              const int* __restrict__ inst,
                                              const int* __restrict__ cent,
                                              u64* __restrict__ statsI,
                                              u64* __restrict__ centI) {
  __shared__ u32 sh[64 * SSTR];  // 30976 B
  const int lane = threadIdx.x;
  const int b = blockIdx.y;
  for (int i = lane; i < 64 * SSTR; i += 64) sh[i] = 0u;
  __syncthreads();
  u32* my = sh + lane * SSTR;

  const float* p3 = pred + ((size_t)b * C_ + 3) * V_;
  const float* p4 = pred + ((size_t)b * C_ + 4) * V_;
  const float* p5 = pred + ((size_t)b * C_ + 5) * V_;
  const int* ib = inst + (size_t)b * V_;
  const int* cb = cent + (size_t)b * V_;

  // grid (1024, B): 8 quads/lane = 32 voxels/lane (packing bounds require <=32)
  for (int g = blockIdx.x * 64 + lane; g < V_ / 4; g += 1024 * 64) {
    const float4 a = ((const float4*)p3)[g];
    const float4 bq = ((const float4*)p4)[g];
    const float4 c = ((const float4*)p5)[g];
    const int4 iv = ((const int4*)ib)[g];
    const int4 cv = ((const int4*)cb)[g];
    const float a0[4] = {a.x, a.y, a.z, a.w};
    const float a1[4] = {bq.x, bq.y, bq.z, bq.w};
    const float a2[4] = {c.x, c.y, c.z, c.w};
    const int iA[4] = {iv.x, iv.y, iv.z, iv.w};
    const int cA[4] = {cv.x, cv.y, cv.z, cv.w};
    const int v0 = g * 4;
#pragma unroll
    for (int j = 0; j < 4; ++j) {
      const int v = v0 + j;
      const u32 xi = v & 255, yi = (v >> 8) & 255, zi = v >> 16;
      const int s = iA[j];
      const float s0 = fminf(fmaxf(a0[j], -8.0f), 8.0f);
      const float s1 = fminf(fmaxf(a1[j], -8.0f), 8.0f);
      const float s2 = fminf(fmaxf(a2[j], -8.0f), 8.0f);
      const u32 q0 = (u32)__float2int_rn((s0 + 8.0f) * QS);  // <=65536
      const u32 q1 = (u32)__float2int_rn((s1 + 8.0f) * QS);
      const u32 q2 = (u32)__float2int_rn((s2 + 8.0f) * QS);
      const u32 r0 = (u32)__float2int_rn(s0 * s0 * RS);      // <=131072
      const u32 r1 = (u32)__float2int_rn(s1 * s1 * RS);
      const u32 r2 = (u32)__float2int_rn(s2 * s2 * RS);
      u32* cc = my + s * SFLD;
      // plain RMW, 7 distinct addresses (no atomics; lane-private region)
      u32 w0 = cc[0], w1 = cc[1], w2 = cc[2], w3 = cc[3], w4 = cc[4], w5 = cc[5], w6 = cc[6];
      cc[0] = w0 + (1u | (xi << 6) | (yi << 19));  // cnt(6b) Sx(13b) Sy(13b)
      cc[1] = w1 + (zi | (q0 << 10));              // Sz(10b) Sq0(22b)
      cc[2] = w2 + q1;
      cc[3] = w3 + q2;
      cc[4] = w4 + r0;
      cc[5] = w5 + r1;
      cc[6] = w6 + r2;
      if (cA[j] != 0) {  // ~1 voxel per batch (bernoulli 2e-7)
        u64* ce = centI + (size_t)(b * NS_ + s) * 4;
        atomicAdd(ce + 0, 1ull);
        atomicAdd(ce + 1, (u64)xi);
        atomicAdd(ce + 2, (u64)yi);
        atomicAdd(ce + 3, (u64)zi);
      }
    }
  }
  __syncthreads();
  // flush: lane sums word-columns w = lane and lane+64 across the 64 replicas.
  // column reads are conflict-free (fixed r, consecutive w across lanes).
#pragma unroll
  for (int cidx = 0; cidx < 2; ++cidx) {
    const int w = lane + cidx * 64;
    if (w < NS_ * SFLD) {
      const int s = w / 7, f = w - s * 7;
      u64 A = 0, Bv = 0, Cv = 0;
      for (int r = 0; r < 64; ++r) {
        const u32 v = sh[r * SSTR + w];
        if (f == 0)      { A += v & 63u; Bv += (v >> 6) & 8191u; Cv += v >> 19; }
        else if (f == 1) { A += v & 1023u; Bv += v >> 10; }
        else             { A += v; }
      }
      u64* dst = statsI + (size_t)(b * NS_ + s) * 10;
      if (f == 0)      { atomicAdd(dst + 0, A); atomicAdd(dst + 1, Bv); atomicAdd(dst + 2, Cv); }
      else if (f == 1) { atomicAdd(dst + 3, A); atomicAdd(dst + 4, Bv); }
      else             { atomicAdd(dst + 3 + f, A); }
    }
  }
}

// ---------------- kernel 2: finalize (fp64, plain stores) ----------------
__global__ void k_finalize(const u64* __restrict__ statsI, const u64* __restrict__ centI,
                           float* __restrict__ params, float* __restrict__ Pcnt,
                           float* __restrict__ varsum) {
  const int t = threadIdx.x;  // block = 64 (one wave)
  double varm = 0.0;
  if (t < B_ * NS_) {
    const int b = t / NS_, s = t % NS_;
    const u64* st = statsI + (size_t)(b * NS_ + s) * 10;
    const double cnt = (double)st[0];
    const double inv = 1.0 / fmax(cnt, 1.0);
    const double xm = (double)st[1] * (1.0 / 1023.0) * inv;
    const double ym = (double)st[2] * (1.0 / 1023.0) * inv;
    const double zm = (double)st[3] * (1.0 / 31.0) * inv;
    const double S0 = (double)st[4] * (1.0 / 4096.0) - 8.0 * cnt;
    const double S1 = (double)st[5] * (1.0 / 4096.0) - 8.0 * cnt;
    const double S2 = (double)st[6] * (1.0 / 4096.0) - 8.0 * cnt;
    const double R0 = (double)st[7] * (1.0 / 2048.0);
    const double R1 = (double)st[8] * (1.0 / 2048.0);
    const double R2 = (double)st[9] * (1.0 / 2048.0);
    const double m0 = S0 * inv, m1 = S1 * inv, m2 = S2 * inv;
    const double v0 = (R0 - 2.0 * m0 * S0 + cnt * m0 * m0) * inv;
    const double v1 = (R1 - 2.0 * m1 * S1 + cnt * m1 * m1) * inv;
    const double v2 = (R2 - 2.0 * m2 * S2 + cnt * m2 * m2) * inv;
    if (s >= 1) {
      const u64* ce = centI + (size_t)(b * NS_ + s) * 4;
      const bool one = (ce[0] == 1ull);
      float* pp = params + (b * NI_ + (s - 1)) * 6;
      pp[0] = (float)(one ? (double)ce[1] * (1.0 / 1023.0) : xm);
      pp[1] = (float)(one ? (double)ce[2] * (1.0 / 1023.0) : ym);
      pp[2] = (float)(one ? (double)ce[3] * (1.0 / 31.0) : zm);
      pp[3] = (float)exp(10.0 * m0);
      pp[4] = (float)exp(10.0 * m1);
      pp[5] = (float)exp(10.0 * m2);
      Pcnt[b * NI_ + (s - 1)] = (float)cnt;
      varm = 0.3125 * (v0 + v1 + v2) * (1.0 / 3.0);  // 0.5 * W_VAR(10)/16 * mean_ch
    }
  }
  double acc = varm;
  for (int off = 32; off > 0; off >>= 1) acc += __shfl_down(acc, off);
  if (t == 0) *varsum = (float)acc;
}

// ---------------- kernel 3: dist + per-lane u8 histograms + seed loss ----------------
__global__ __launch_bounds__(64) void k_hist(const float* __restrict__ pred,
                                             const int* __restrict__ inst,
                                             const int* __restrict__ lab,
                                             const float* __restrict__ params,
                                             u32* __restrict__ Hg,
                                             u64* __restrict__ seedI) {
  __shared__ unsigned char hb[64 * HSTR_B];  // 33024 B
  const int lane = threadIdx.x;
  const int b = blockIdx.y;
  {
    u32* z = (u32*)hb;
    for (int i = lane; i < 64 * HSTR_W; i += 64) z[i] = 0u;
  }
  __syncthreads();
  unsigned char* my = hb + lane * HSTR_B;

  float pc0[NI_], pc1[NI_], pc2[NI_], ps0[NI_], ps1[NI_], ps2[NI_];
#pragma unroll
  for (int n = 0; n < NI_; ++n) {
    const float* pp = params + (b * NI_ + n) * 6;
    pc0[n] = pp[0]; pc1[n] = pp[1]; pc2[n] = pp[2];
    ps0[n] = pp[3]; ps1[n] = pp[4]; ps2[n] = pp[5];
  }

  const float* p0 = pred + ((size_t)b * C_ + 0) * V_;
  const float* p1 = pred + ((size_t)b * C_ + 1) * V_;
  const float* p2 = pred + ((size_t)b * C_ + 2) * V_;
  const float* p6 = pred + ((size_t)b * C_ + 6) * V_;
  const int* ib = inst + (size_t)b * V_;
  const int* lb = lab + (size_t)b * V_;

  float bgacc = 0.0f, fgacc = 0.0f;
  // grid (1024, B): 8 quads/lane = 32 voxels/lane (u8 bins hold <=32)
  for (int g = blockIdx.x * 64 + lane; g < V_ / 4; g += 1024 * 64) {
    const float4 f0 = ((const float4*)p0)[g];
    const float4 f1 = ((const float4*)p1)[g];
    const float4 f2 = ((const float4*)p2)[g];
    const float4 f6 = ((const float4*)p6)[g];
    const int4 iv = ((const int4*)ib)[g];
    const int4 lv = ((const int4*)lb)[g];
    const float a0[4] = {f0.x, f0.y, f0.z, f0.w};
    const float a1[4] = {f1.x, f1.y, f1.z, f1.w};
    const float a2[4] = {f2.x, f2.y, f2.z, f2.w};
    const float a6[4] = {f6.x, f6.y, f6.z, f6.w};
    const int iA[4] = {iv.x, iv.y, iv.z, iv.w};
    const int lA[4] = {lv.x, lv.y, lv.z, lv.w};
    const int v0 = g * 4;
#pragma unroll
    for (int j = 0; j < 4; ++j) {
      const int v = v0 + j;
      // fast tanh: 1 - 2/(e^{2x}+1)
      const float t0 = __expf(2.0f * a0[j]);
      const float t1 = __expf(2.0f * a1[j]);
      const float t2 = __expf(2.0f * a2[j]);
      const float e0 = 1.0f - 2.0f / (t0 + 1.0f) + (float)(v & 255) * (1.0f / 1023.0f);
      const float e1 = 1.0f - 2.0f / (t1 + 1.0f) + (float)((v >> 8) & 255) * (1.0f / 1023.0f);
      const float e2 = 1.0f - 2.0f / (t2 + 1.0f) + (float)(v >> 16) * (1.0f / 31.0f);
      const float sd = 1.0f / (1.0f + __expf(-a6[j]));
      const int is = iA[j];
      float down = 0.0f;
      int offs[NI_];
#pragma unroll
      for (int n = 0; n < NI_; ++n) {
        const float d0 = e0 - pc0[n];
        const float d1 = e1 - pc1[n];
        const float d2 = e2 - pc2[n];
        const float q = ps0[n] * d0 * d0 + ps1[n] * d1 * d1 + ps2[n] * d2 * d2;
        const float d = __expf(-q);
        const bool pos = (is == n + 1);
        if (pos) down = d;
        const float err = pos ? fmaf(-2.0f, d, 2.0f) : 2.0f * d;
        int bin = (int)(err * BSCALE);
        bin = bin > NB - 1 ? NB - 1 : bin;
        offs[n] = n * 32 + (pos ? 16 : 0) + bin;  // u8 offset in lane region
      }
      unsigned char vals[NI_];
#pragma unroll
      for (int n = 0; n < NI_; ++n) vals[n] = my[offs[n]];  // 16 distinct bytes (n-stride 32)
#pragma unroll
      for (int n = 0; n < NI_; ++n) my[offs[n]] = (unsigned char)(vals[n] + 1);
      if (lA[j] == 0) bgacc = fmaf(sd, sd, bgacc);
      if (is > 0) {
        const float tdiff = sd - down;
        fgacc = fmaf(tdiff, tdiff, fgacc);
      }
    }
  }
  __syncthreads();
  // flush: lane sums u32-word columns w = lane, lane+64 across 64 replicas (u16-SWAR)
  const u32* sh32 = (const u32*)hb;
#pragma unroll
  for (int cidx = 0; cidx < 2; ++cidx) {
    const int w = lane + cidx * 64;  // 0..127 used (word 128 = pad)
    u32 lo = 0, hi = 0;
    for (int r = 0; r < 64; ++r) {
      const u32 vv = sh32[r * HSTR_W + w];
      lo += vv & 0x00FF00FFu;
      hi += (vv >> 8) & 0x00FF00FFu;
    }
    u32* H = Hg + b * 512 + w * 4;
    atomicAdd(H + 0, lo & 0xFFFFu);
    atomicAdd(H + 2, lo >> 16);
    atomicAdd(H + 1, hi & 0xFFFFu);
    atomicAdd(H + 3, hi >> 16);
  }
  // seed-loss wave reduction -> one u64 fixed-point atomic per block
  float bgw = bgacc, fgw = fgacc;
  for (int off = 32; off > 0; off >>= 1) {
    bgw += __shfl_down(bgw, off);
    fgw += __shfl_down(fgw, off);
  }
  if (lane == 0) {
    const double sacc = (double)bgw + 10.0 * (double)fgw;
    atomicAdd(seedI, (u64)(sacc * SEED_SCALE + 0.5));
  }
}

// ---------------- kernel 4: binned lovasz scan + final sum ----------------
__global__ void k_final(const u32* __restrict__ Hg, const float* __restrict__ Pcnt,
                        const float* __restrict__ varsum, const u64* __restrict__ seedI,
                        float* __restrict__ out) {
  const int t = threadIdx.x;  // block = 64
  float loss = 0.0f;
  if (t < B_ * NI_) {
    const int b = t / NI_, n = t % NI_;
    const u32* H = Hg + b * 512 + n * 32;  // [0..15] neg bins, [16..31] pos bins
    const float P = Pcnt[t];
    float k = 0.0f, f = 0.0f, jprev = 0.0f;
    for (int i = NB - 1; i >= 0; --i) {
      k += (float)H[16 + i];
      f += (float)H[i];
      const float jnew = (k + f > 0.0f) ? (1.0f - (P - k) / (P + f)) : 0.0f;
      loss += ((float)i + 0.5f) * BINW * (jnew - jprev);
      jprev = jnew;
    }
  }
  for (int off = 32; off > 0; off >>= 1) loss += __shfl_down(loss, off);
  if (t == 0) {
    const double total = (double)loss * 0.03125                     // 0.5 * W_INST / 16
                       + (double)(*varsum)
                       + (double)(*seedI) * (1.0 / SEED_SCALE) * 0.5 / (double)V_;
    out[0] = (float)total;
  }
}

// ---------------- launch ----------------
extern "C" void kernel_launch(void* const* d_in, const int* in_sizes, int n_in,
                              void* d_out, int out_size, void* d_ws, size_t ws_size,
                              hipStream_t stream) {
  const float* pred = (const float*)d_in[0];
  const int* inst = (const int*)d_in[1];
  const int* lab = (const int*)d_in[2];
  const int* cent = (const int*)d_in[3];
  float* out = (float*)d_out;

  char* ws = (char*)d_ws;
  u64* statsI = (u64*)(ws + 0);          // B*17*10 u64 = 2720 B
  u64* centI = (u64*)(ws + 4096);        // B*17*4 u64 = 1088 B
  float* params = (float*)(ws + 8192);   // B*16*6 f32
  float* Pcnt = (float*)(ws + 9216);     // B*16 f32
  float* varsum = (float*)(ws + 9472);   // 1 f32
  u64* seedI = (u64*)(ws + 9480);        // 1 u64
  u32* Hg = (u32*)(ws + 12288);          // B*512 u32 = 4096 B

  hipMemsetAsync(d_ws, 0, 16384, stream);

  k_stats<<<dim3(1024, B_), 64, 0, stream>>>(pred, inst, cent, statsI, centI);
  k_finalize<<<1, 64, 0, stream>>>(statsI, centI, params, Pcnt, varsum);
  k_hist<<<dim3(1024, B_), 64, 0, stream>>>(pred, inst, lab, params, Hg, seedI);
  k_final<<<1, 64, 0, stream>>>(Hg, Pcnt, varsum, seedI, out);
}

// Round 12
// 564.122 us; speedup vs baseline: 1.0029x; 1.0029x over previous
//
#include <hip/hip_runtime.h>

typedef unsigned long long u64;
typedef unsigned int u32;

// ---------------- problem constants ----------------
constexpr int B_ = 2;
constexpr int C_ = 7;
constexpr int V_ = 32 * 256 * 256;        // 2097152
constexpr int NS_ = 17;                   // segments incl background
constexpr int NI_ = 16;                   // instances

// lovasz histogram: 8 bins over err in [0,2]
constexpr int NB = 8;
constexpr float BSCALE = 4.0f;            // err*4 -> bin
constexpr float BINW = 0.25f;

// k_stats per-lane LDS: 17 segs x 5 packed u32 fields, stride 87 (odd -> 2-way banks)
// 16 voxels/lane. w0: cnt(5b)|Sx(12b)|Sy(12b)  w1: Sz(u16)|Sq0(u16)
// w2: Sq1|Sq2  w3: Sr0|Sr1  w4: Sr2
constexpr int SFLD = 5;
constexpr int SSTR = NS_ * SFLD + 2;      // 87 words; LDS 64*87*4 = 22272 B -> 7 blk/CU
constexpr float QS = 64.0f;               // (sig+8)*64 <= 1024; sum16 <= 16384 < 2^16
constexpr float RS = 16.0f;               // sig^2*16  <= 1024; sum16 <= 16384 < 2^16
constexpr double SEED_SCALE = 16777216.0; // 2^24

// k_hist per-lane LDS: [16 inst][2][8 bins] u8 = 256 B + 4 pad = 260 B (65 words, odd)
constexpr int HSTR_B = 260;
constexpr int HSTR_W = 65;                // LDS 64*260 = 16640 B -> 9 blk/CU

// ---------------- kernel 1: segmented stats (per-lane LDS, plain RMW, 5 words) ----------------
// statsI per (b,s): 0 cnt | 1 Sx | 2 Sy | 3 Sz | 4 Sq0 | 5 Sq1 | 6 Sq2 | 7 Sr0 | 8 Sr1 | 9 Sr2
__global__ __launch_bounds__(64) void k_stats(const float* __restrict__ pred,
                                              const int* __restrict__ inst,
                                              const int* __restrict__ cent,
                                              u64* __restrict__ statsI,
                                              u64* __restrict__ centI) {
  __shared__ u32 sh[64 * SSTR];  // 22272 B
  const int lane = threadIdx.x;
  const int b = blockIdx.y;
  for (int i = lane; i < 64 * SSTR; i += 64) sh[i] = 0u;
  __syncthreads();
  u32* my = sh + lane * SSTR;

  const float* p3 = pred + ((size_t)b * C_ + 3) * V_;
  const float* p4 = pred + ((size_t)b * C_ + 4) * V_;
  const float* p5 = pred + ((size_t)b * C_ + 5) * V_;
  const int* ib = inst + (size_t)b * V_;
  const int* cb = cent + (size_t)b * V_;

  // grid (2048, B): 4 quads/lane = 16 voxels/lane (packing bounds require <=16)
  for (int g = blockIdx.x * 64 + lane; g < V_ / 4; g += 2048 * 64) {
    const float4 a = ((const float4*)p3)[g];
    const float4 bq = ((const float4*)p4)[g];
    const float4 c = ((const float4*)p5)[g];
    const int4 iv = ((const int4*)ib)[g];
    const int4 cv = ((const int4*)cb)[g];
    const float a0[4] = {a.x, a.y, a.z, a.w};
    const float a1[4] = {bq.x, bq.y, bq.z, bq.w};
    const float a2[4] = {c.x, c.y, c.z, c.w};
    const int iA[4] = {iv.x, iv.y, iv.z, iv.w};
    const int cA[4] = {cv.x, cv.y, cv.z, cv.w};
    const int v0 = g * 4;
#pragma unroll
    for (int j = 0; j < 4; ++j) {
      const int v = v0 + j;
      const u32 xi = v & 255, yi = (v >> 8) & 255, zi = v >> 16;
      const int s = iA[j];
      const float s0 = fminf(fmaxf(a0[j], -8.0f), 8.0f);
      const float s1 = fminf(fmaxf(a1[j], -8.0f), 8.0f);
      const float s2 = fminf(fmaxf(a2[j], -8.0f), 8.0f);
      const u32 q0 = (u32)__float2int_rn((s0 + 8.0f) * QS);  // <=1024
      const u32 q1 = (u32)__float2int_rn((s1 + 8.0f) * QS);
      const u32 q2 = (u32)__float2int_rn((s2 + 8.0f) * QS);
      const u32 r0 = (u32)__float2int_rn(s0 * s0 * RS);      // <=1024
      const u32 r1 = (u32)__float2int_rn(s1 * s1 * RS);
      const u32 r2 = (u32)__float2int_rn(s2 * s2 * RS);
      u32* cc = my + s * SFLD;
      // plain RMW, 5 distinct addresses (no atomics; lane-private region)
      u32 w0 = cc[0], w1 = cc[1], w2 = cc[2], w3 = cc[3], w4 = cc[4];
      cc[0] = w0 + (1u | (xi << 5) | (yi << 17));
      cc[1] = w1 + (zi | (q0 << 16));
      cc[2] = w2 + (q1 | (q2 << 16));
      cc[3] = w3 + (r0 | (r1 << 16));
      cc[4] = w4 + r2;
      if (cA[j] != 0) {  // ~1 voxel per batch (bernoulli 2e-7)
        u64* ce = centI + (size_t)(b * NS_ + s) * 4;
        atomicAdd(ce + 0, 1ull);
        atomicAdd(ce + 1, (u64)xi);
        atomicAdd(ce + 2, (u64)yi);
        atomicAdd(ce + 3, (u64)zi);
      }
    }
  }
  __syncthreads();
  // flush: lane sums word-columns w = lane, lane+64 across the 64 replicas (conflict-free)
#pragma unroll
  for (int cidx = 0; cidx < 2; ++cidx) {
    const int w = lane + cidx * 64;
    if (w < NS_ * SFLD) {
      const int s = w / SFLD, f = w - s * SFLD;
      u64 A = 0, Bv = 0, Cv = 0;
      for (int r = 0; r < 64; ++r) {
        const u32 v = sh[r * SSTR + w];
        if (f == 0)      { A += v & 31u; Bv += (v >> 5) & 4095u; Cv += v >> 17; }
        else if (f == 4) { A += v; }
        else             { A += v & 0xFFFFu; Bv += v >> 16; }
      }
      u64* dst = statsI + (size_t)(b * NS_ + s) * 10;
      if (f == 0)      { atomicAdd(dst + 0, A); atomicAdd(dst + 1, Bv); atomicAdd(dst + 2, Cv); }
      else if (f == 1) { atomicAdd(dst + 3, A); atomicAdd(dst + 4, Bv); }
      else if (f == 2) { atomicAdd(dst + 5, A); atomicAdd(dst + 6, Bv); }
      else if (f == 3) { atomicAdd(dst + 7, A); atomicAdd(dst + 8, Bv); }
      else             { atomicAdd(dst + 9, A); }
    }
  }
}

// ---------------- kernel 2: finalize (fp64, plain stores) ----------------
__global__ void k_finalize(const u64* __restrict__ statsI, const u64* __restrict__ centI,
                           float* __restrict__ params, float* __restrict__ Pcnt,
                           float* __restrict__ varsum) {
  const int t = threadIdx.x;  // block = 64 (one wave)
  double varm = 0.0;
  if (t < B_ * NS_) {
    const int b = t / NS_, s = t % NS_;
    const u64* st = statsI + (size_t)(b * NS_ + s) * 10;
    const double cnt = (double)st[0];
    const double inv = 1.0 / fmax(cnt, 1.0);
    const double xm = (double)st[1] * (1.0 / 1023.0) * inv;
    const double ym = (double)st[2] * (1.0 / 1023.0) * inv;
    const double zm = (double)st[3] * (1.0 / 31.0) * inv;
    const double S0 = (double)st[4] * (1.0 / 64.0) - 8.0 * cnt;  // sum sig0
    const double S1 = (double)st[5] * (1.0 / 64.0) - 8.0 * cnt;
    const double S2 = (double)st[6] * (1.0 / 64.0) - 8.0 * cnt;
    const double R0 = (double)st[7] * (1.0 / 16.0);              // sum sig0^2
    const double R1 = (double)st[8] * (1.0 / 16.0);
    const double R2 = (double)st[9] * (1.0 / 16.0);
    const double m0 = S0 * inv, m1 = S1 * inv, m2 = S2 * inv;
    const double v0 = (R0 - 2.0 * m0 * S0 + cnt * m0 * m0) * inv;
    const double v1 = (R1 - 2.0 * m1 * S1 + cnt * m1 * m1) * inv;
    const double v2 = (R2 - 2.0 * m2 * S2 + cnt * m2 * m2) * inv;
    if (s >= 1) {
      const u64* ce = centI + (size_t)(b * NS_ + s) * 4;
      const bool one = (ce[0] == 1ull);
      float* pp = params + (b * NI_ + (s - 1)) * 6;
      pp[0] = (float)(one ? (double)ce[1] * (1.0 / 1023.0) : xm);
      pp[1] = (float)(one ? (double)ce[2] * (1.0 / 1023.0) : ym);
      pp[2] = (float)(one ? (double)ce[3] * (1.0 / 31.0) : zm);
      pp[3] = (float)exp(10.0 * m0);
      pp[4] = (float)exp(10.0 * m1);
      pp[5] = (float)exp(10.0 * m2);
      Pcnt[b * NI_ + (s - 1)] = (float)cnt;
      varm = 0.3125 * (v0 + v1 + v2) * (1.0 / 3.0);  // 0.5 * W_VAR(10)/16 * mean_ch
    }
  }
  double acc = varm;
  for (int off = 32; off > 0; off >>= 1) acc += __shfl_down(acc, off);
  if (t == 0) *varsum = (float)acc;
}

// ---------------- kernel 3: dist + per-lane u8 8-bin histograms + seed loss ----------------
__global__ __launch_bounds__(64) void k_hist(const float* __restrict__ pred,
                                             const int* __restrict__ inst,
                                             const int* __restrict__ lab,
                                             const float* __restrict__ params,
                                             u32* __restrict__ Hg,
                                             u64* __restrict__ seedI) {
  __shared__ unsigned char hb[64 * HSTR_B];  // 16640 B -> 9 blocks/CU
  const int lane = threadIdx.x;
  const int b = blockIdx.y;
  {
    u32* z = (u32*)hb;
    for (int i = lane; i < 64 * HSTR_W; i += 64) z[i] = 0u;
  }
  __syncthreads();
  unsigned char* my = hb + lane * HSTR_B;

  float pc0[NI_], pc1[NI_], pc2[NI_], ps0[NI_], ps1[NI_], ps2[NI_];
#pragma unroll
  for (int n = 0; n < NI_; ++n) {
    const float* pp = params + (b * NI_ + n) * 6;
    pc0[n] = pp[0]; pc1[n] = pp[1]; pc2[n] = pp[2];
    ps0[n] = pp[3]; ps1[n] = pp[4]; ps2[n] = pp[5];
  }

  const float* p0 = pred + ((size_t)b * C_ + 0) * V_;
  const float* p1 = pred + ((size_t)b * C_ + 1) * V_;
  const float* p2 = pred + ((size_t)b * C_ + 2) * V_;
  const float* p6 = pred + ((size_t)b * C_ + 6) * V_;
  const int* ib = inst + (size_t)b * V_;
  const int* lb = lab + (size_t)b * V_;

  float bgacc = 0.0f, fgacc = 0.0f;
  // grid (1024, B): 8 quads/lane = 32 voxels/lane (u8 bins hold <=32)
  for (int g = blockIdx.x * 64 + lane; g < V_ / 4; g += 1024 * 64) {
    const float4 f0 = ((const float4*)p0)[g];
    const float4 f1 = ((const float4*)p1)[g];
    const float4 f2 = ((const float4*)p2)[g];
    const float4 f6 = ((const float4*)p6)[g];
    const int4 iv = ((const int4*)ib)[g];
    const int4 lv = ((const int4*)lb)[g];
    const float a0[4] = {f0.x, f0.y, f0.z, f0.w};
    const float a1[4] = {f1.x, f1.y, f1.z, f1.w};
    const float a2[4] = {f2.x, f2.y, f2.z, f2.w};
    const float a6[4] = {f6.x, f6.y, f6.z, f6.w};
    const int iA[4] = {iv.x, iv.y, iv.z, iv.w};
    const int lA[4] = {lv.x, lv.y, lv.z, lv.w};
    const int v0 = g * 4;
#pragma unroll
    for (int j = 0; j < 4; ++j) {
      const int v = v0 + j;
      // fast tanh: 1 - 2/(e^{2x}+1)
      const float t0 = __expf(2.0f * a0[j]);
      const float t1 = __expf(2.0f * a1[j]);
      const float t2 = __expf(2.0f * a2[j]);
      const float e0 = 1.0f - 2.0f / (t0 + 1.0f) + (float)(v & 255) * (1.0f / 1023.0f);
      const float e1 = 1.0f - 2.0f / (t1 + 1.0f) + (float)((v >> 8) & 255) * (1.0f / 1023.0f);
      const float e2 = 1.0f - 2.0f / (t2 + 1.0f) + (float)(v >> 16) * (1.0f / 31.0f);
      const float sd = 1.0f / (1.0f + __expf(-a6[j]));
      const int is = iA[j];
      float down = 0.0f;
      int offs[NI_];
#pragma unroll
      for (int n = 0; n < NI_; ++n) {
        const float d0 = e0 - pc0[n];
        const float d1 = e1 - pc1[n];
        const float d2 = e2 - pc2[n];
        const float q = ps0[n] * d0 * d0 + ps1[n] * d1 * d1 + ps2[n] * d2 * d2;
        const float d = __expf(-q);
        const bool pos = (is == n + 1);
        if (pos) down = d;
        const float err = pos ? fmaf(-2.0f, d, 2.0f) : 2.0f * d;
        int bin = (int)(err * BSCALE);
        bin = bin > NB - 1 ? NB - 1 : bin;
        offs[n] = n * 16 + (pos ? 8 : 0) + bin;  // u8 offset in lane region
      }
      unsigned char vals[NI_];
#pragma unroll
      for (int n = 0; n < NI_; ++n) vals[n] = my[offs[n]];  // 16 distinct bytes (n-stride 16)
#pragma unroll
      for (int n = 0; n < NI_; ++n) my[offs[n]] = (unsigned char)(vals[n] + 1);
      if (lA[j] == 0) bgacc = fmaf(sd, sd, bgacc);
      if (is > 0) {
        const float tdiff = sd - down;
        fgacc = fmaf(tdiff, tdiff, fgacc);
      }
    }
  }
  __syncthreads();
  // flush: lane sums u32-word column w = lane across 64 replicas (u16-SWAR)
  const u32* sh32 = (const u32*)hb;
  {
    const int w = lane;  // words 0..63 used (word 64 = pad)
    u32 lo = 0, hi = 0;
    for (int r = 0; r < 64; ++r) {
      const u32 vv = sh32[r * HSTR_W + w];
      lo += vv & 0x00FF00FFu;
      hi += (vv >> 8) & 0x00FF00FFu;
    }
    u32* H = Hg + b * 256 + w * 4;
    atomicAdd(H + 0, lo & 0xFFFFu);
    atomicAdd(H + 2, lo >> 16);
    atomicAdd(H + 1, hi & 0xFFFFu);
    atomicAdd(H + 3, hi >> 16);
  }
  // seed-loss wave reduction -> one u64 fixed-point atomic per block
  float bgw = bgacc, fgw = fgacc;
  for (int off = 32; off > 0; off >>= 1) {
    bgw += __shfl_down(bgw, off);
    fgw += __shfl_down(fgw, off);
  }
  if (lane == 0) {
    const double sacc = (double)bgw + 10.0 * (double)fgw;
    atomicAdd(seedI, (u64)(sacc * SEED_SCALE + 0.5));
  }
}

// ---------------- kernel 4: binned lovasz scan + final sum ----------------
__global__ void k_final(const u32* __restrict__ Hg, const float* __restrict__ Pcnt,
                        const float* __restrict__ varsum, const u64* __restrict__ seedI,
                        float* __restrict__ out) {
  const int t = threadIdx.x;  // block = 64
  float loss = 0.0f;
  if (t < B_ * NI_) {
    const int b = t / NI_, n = t % NI_;
    const u32* H = Hg + b * 256 + n * 16;  // [0..7] neg bins, [8..15] pos bins
    const float P = Pcnt[t];
    float k = 0.0f, f = 0.0f, jprev = 0.0f;
    for (int i = NB - 1; i >= 0; --i) {
      k += (float)H[NB + i];
      f += (float)H[i];
      const float jnew = (k + f > 0.0f) ? (1.0f - (P - k) / (P + f)) : 0.0f;
      loss += ((float)i + 0.5f) * BINW * (jnew - jprev);
      jprev = jnew;
    }
  }
  for (int off = 32; off > 0; off >>= 1) loss += __shfl_down(loss, off);
  if (t == 0) {
    const double total = (double)loss * 0.03125                     // 0.5 * W_INST / 16
                       + (double)(*varsum)
                       + (double)(*seedI) * (1.0 / SEED_SCALE) * 0.5 / (double)V_;
    out[0] = (float)total;
  }
}

// ---------------- launch ----------------
extern "C" void kernel_launch(void* const* d_in, const int* in_sizes, int n_in,
                              void* d_out, int out_size, void* d_ws, size_t ws_size,
                              hipStream_t stream) {
  const float* pred = (const float*)d_in[0];
  const int* inst = (const int*)d_in[1];
  const int* lab = (const int*)d_in[2];
  const int* cent = (const int*)d_in[3];
  float* out = (float*)d_out;

  char* ws = (char*)d_ws;
  u64* statsI = (u64*)(ws + 0);          // B*17*10 u64 = 2720 B
  u64* centI = (u64*)(ws + 4096);        // B*17*4 u64 = 1088 B
  float* params = (float*)(ws + 8192);   // B*16*6 f32
  float* Pcnt = (float*)(ws + 9216);     // B*16 f32
  float* varsum = (float*)(ws + 9472);   // 1 f32
  u64* seedI = (u64*)(ws + 9480);        // 1 u64
  u32* Hg = (u32*)(ws + 10240);          // B*256 u32 = 2048 B

  hipMemsetAsync(d_ws, 0, 16384, stream);

  k_stats<<<dim3(2048, B_), 64, 0, stream>>>(pred, inst, cent, statsI, centI);
  k_finalize<<<1, 64, 0, stream>>>(statsI, centI, params, Pcnt, varsum);
  k_hist<<<dim3(1024, B_), 64, 0, stream>>>(pred, inst, lab, params, Hg, seedI);
  k_final<<<1, 64, 0, stream>>>(Hg, Pcnt, varsum, seedI, out);
}